// Round 1
// baseline (54.958 us; speedup 1.0000x reference)
//
#include <hip/hip_runtime.h>

// YOLO loss: predictions (N,7,7,30) f32, target (N,7,7,25) f32 -> scalar f32.
// S=7, B=2, C=20. Memory-bound reduction (~176 MB read -> 1 float).

#define S7 7
#define CELL_P 30   // B*5 + C
#define CELL_T 25   // 5 + C

__global__ __launch_bounds__(256) void yolo_cell_kernel(
    const float* __restrict__ pred, const float* __restrict__ tgt,
    float* __restrict__ partial, int ncells)
{
    int cell = blockIdx.x * 256 + threadIdx.x;
    float loss = 0.0f;
    if (cell < ncells) {
        const float* p = pred + (long long)cell * CELL_P;
        const float* t = tgt  + (long long)cell * CELL_T;

        // pred row: 30 f32 = 120 B, cell*120 is 8B-aligned -> float2 loads
        float pv[CELL_P];
        #pragma unroll
        for (int k = 0; k < CELL_P / 2; ++k) {
            float2 v = reinterpret_cast<const float2*>(p)[k];
            pv[2 * k]     = v.x;
            pv[2 * k + 1] = v.y;
        }
        // target row: 25 f32 = 100 B, odd cells only 4B-aligned -> scalar loads
        float tv[CELL_T];
        #pragma unroll
        for (int k = 0; k < CELL_T; ++k) tv[k] = t[k];

        int rem  = cell % 49;           // within-sample cell
        float gx = (float)(rem % S7);   // column (axis 2)
        float gy = (float)(rem / S7);   // row    (axis 1)

        float obj = (tv[4] > 0.5f) ? 1.0f : 0.0f;

        // ground-truth corners
        float gcx = (gx + tv[0]) * 64.0f;
        float gcy = (gy + tv[1]) * 64.0f;
        float gw  = tv[2] * 448.0f;
        float gh  = tv[3] * 448.0f;
        float gx1 = gcx - gw * 0.5f, gy1 = gcy - gh * 0.5f;
        float gx2 = gcx + gw * 0.5f, gy2 = gcy + gh * 0.5f;
        float ga  = gw * gh;

        float iou[2], dxy[2], dwh[2], conf[2];
        #pragma unroll
        for (int b = 0; b < 2; ++b) {
            const float* pb = pv + b * 5;
            float pcx = (gx + pb[0]) * 64.0f;
            float pcy = (gy + pb[1]) * 64.0f;
            float pw  = pb[2] * 448.0f;
            float ph  = pb[3] * 448.0f;
            float px1 = pcx - pw * 0.5f, py1 = pcy - ph * 0.5f;
            float px2 = pcx + pw * 0.5f, py2 = pcy + ph * 0.5f;
            float pa  = pw * ph;

            float iw = fmaxf(fminf(px2, gx2) - fmaxf(px1, gx1), 0.0f);
            float ih = fmaxf(fminf(py2, gy2) - fmaxf(py1, gy1), 0.0f);
            float inter = iw * ih;
            iou[b] = inter / (pa + ga - inter + 1e-6f);

            float dx = pb[0] - tv[0], dy = pb[1] - tv[1];
            dxy[b] = dx * dx + dy * dy;
            float sw = sqrtf(fmaxf(pb[2], 0.0f)) - sqrtf(fmaxf(tv[2], 0.0f));
            float sh = sqrtf(fmaxf(pb[3], 0.0f)) - sqrtf(fmaxf(tv[3], 0.0f));
            dwh[b] = sw * sw + sh * sh;
            conf[b] = pb[4];
        }

        // argmax ties -> first index (box 0), matching jnp.argmax
        int best = (iou[1] > iou[0]) ? 1 : 0;

        #pragma unroll
        for (int b = 0; b < 2; ++b) {
            float resp_obj = (b == best) ? obj : 0.0f;
            loss += 5.0f * resp_obj * (dxy[b] + dwh[b]);          // coord
            float d = conf[b] - iou[b];
            loss += resp_obj * d * d;                              // conf obj
            loss += 0.5f * (1.0f - resp_obj) * conf[b] * conf[b];  // conf noobj
        }

        float cls = 0.0f;
        #pragma unroll
        for (int c = 0; c < 20; ++c) {
            float d = pv[10 + c] - tv[5 + c];
            cls += d * d;
        }
        loss += obj * cls;                                          // class
    }

    // wave64 reduce
    #pragma unroll
    for (int off = 32; off > 0; off >>= 1)
        loss += __shfl_down(loss, off, 64);

    __shared__ float smem[4];
    int lane = threadIdx.x & 63;
    int wid  = threadIdx.x >> 6;
    if (lane == 0) smem[wid] = loss;
    __syncthreads();
    if (threadIdx.x == 0)
        partial[blockIdx.x] = smem[0] + smem[1] + smem[2] + smem[3];
}

__global__ __launch_bounds__(256) void yolo_final_kernel(
    const float* __restrict__ partial, int n, float* __restrict__ out, float invN)
{
    float s = 0.0f;
    for (int i = threadIdx.x; i < n; i += 256)
        s += partial[i];
    #pragma unroll
    for (int off = 32; off > 0; off >>= 1)
        s += __shfl_down(s, off, 64);

    __shared__ float smem[4];
    int lane = threadIdx.x & 63;
    int wid  = threadIdx.x >> 6;
    if (lane == 0) smem[wid] = s;
    __syncthreads();
    if (threadIdx.x == 0)
        out[0] = (smem[0] + smem[1] + smem[2] + smem[3]) * invN;
}

extern "C" void kernel_launch(void* const* d_in, const int* in_sizes, int n_in,
                              void* d_out, int out_size, void* d_ws, size_t ws_size,
                              hipStream_t stream)
{
    const float* pred = (const float*)d_in[0];
    const float* tgt  = (const float*)d_in[1];
    float* out        = (float*)d_out;
    float* partial    = (float*)d_ws;

    int ncells = in_sizes[0] / CELL_P;     // N*S*S
    int N      = ncells / 49;
    int blocks = (ncells + 255) / 256;

    yolo_cell_kernel<<<blocks, 256, 0, stream>>>(pred, tgt, partial, ncells);
    yolo_final_kernel<<<1, 256, 0, stream>>>(partial, blocks, out, 1.0f / (float)N);
}

// Round 2
// 40.941 us; speedup vs baseline: 1.3424x; 1.3424x over previous
//
#include <hip/hip_runtime.h>

// YOLO loss: predictions (N,7,7,30) f32, target (N,7,7,25) f32 -> scalar f32.
// S=7, B=2, C=20. Memory-bound reduction (~176 MB -> 1 float).
//
// Round 2: coalesced LDS staging. Round-1 kernel let each lane read its own
// 120B/100B record -> ~64 cache-line transactions per load instr -> 28% BW.
// Now each block stages 256 cells with coalesced float2 loads, transposes
// into LDS rows padded to 31/27 words (coprime with 32 banks -> conflict-free
// reads), then computes per-cell from LDS.

#define S7 7
#define CELL_P 30   // B*5 + C
#define CELL_T 25   // 5 + C
#define PADP 31     // gcd(31,32)=1 -> conflict-free row reads
#define PADT 27     // gcd(27,32)=1

__global__ __launch_bounds__(256) void yolo_cell_kernel(
    const float* __restrict__ pred, const float* __restrict__ tgt,
    float* __restrict__ partial)
{
    __shared__ float sp[256 * PADP];   // 31744 B
    __shared__ float st[256 * PADT];   // 27648 B

    const int t = threadIdx.x;

    // ---- stage pred: 256 cells * 30 f32 = 3840 float2, 15 per thread ----
    {
        const float2* p2 = reinterpret_cast<const float2*>(
            pred + (size_t)blockIdx.x * 256 * CELL_P);
        #pragma unroll
        for (int i = 0; i < 15; ++i) {
            int j2 = t + 256 * i;          // float2 index, < 3840
            float2 v = p2[j2];
            int cell = j2 / 15;            // 30 words/row = 15 float2/row
            int off  = 2 * (j2 - cell * 15);
            sp[cell * PADP + off]     = v.x;
            sp[cell * PADP + off + 1] = v.y;
        }
    }
    // ---- stage tgt: 256 cells * 25 f32 = 3200 float2, 12.5 per thread ----
    {
        const float2* t2 = reinterpret_cast<const float2*>(
            tgt + (size_t)blockIdx.x * 256 * CELL_T);
        #pragma unroll
        for (int i = 0; i < 13; ++i) {
            int j2 = t + 256 * i;
            if (i < 12 || j2 < 3200) {
                float2 v = t2[j2];
                int w  = 2 * j2;           // word index; rows are 25 (odd) so
                int c0 = w / 25;           // a float2 can straddle two rows
                int o0 = w - c0 * 25;
                st[c0 * PADT + o0] = v.x;
                int w1 = w + 1;
                int c1 = w1 / 25;
                int o1 = w1 - c1 * 25;
                st[c1 * PADT + o1] = v.y;
            }
        }
    }
    __syncthreads();

    // ---- per-cell loss from LDS ----
    const float* pv = sp + t * PADP;
    const float* tv = st + t * PADT;

    int cell = blockIdx.x * 256 + t;
    int rem  = cell % 49;
    float gx = (float)(rem % S7);   // column (axis 2)
    float gy = (float)(rem / S7);   // row    (axis 1)

    float obj = (tv[4] > 0.5f) ? 1.0f : 0.0f;

    float gcx = (gx + tv[0]) * 64.0f;
    float gcy = (gy + tv[1]) * 64.0f;
    float gw  = tv[2] * 448.0f;
    float gh  = tv[3] * 448.0f;
    float gx1 = gcx - gw * 0.5f, gy1 = gcy - gh * 0.5f;
    float gx2 = gcx + gw * 0.5f, gy2 = gcy + gh * 0.5f;
    float ga  = gw * gh;

    float iou[2], dxy[2], dwh[2], conf[2];
    #pragma unroll
    for (int b = 0; b < 2; ++b) {
        float b0 = pv[b * 5 + 0], b1 = pv[b * 5 + 1], b2 = pv[b * 5 + 2];
        float b3 = pv[b * 5 + 3], b4 = pv[b * 5 + 4];
        float pcx = (gx + b0) * 64.0f;
        float pcy = (gy + b1) * 64.0f;
        float pw  = b2 * 448.0f;
        float ph  = b3 * 448.0f;
        float px1 = pcx - pw * 0.5f, py1 = pcy - ph * 0.5f;
        float px2 = pcx + pw * 0.5f, py2 = pcy + ph * 0.5f;
        float pa  = pw * ph;

        float iw = fmaxf(fminf(px2, gx2) - fmaxf(px1, gx1), 0.0f);
        float ih = fmaxf(fminf(py2, gy2) - fmaxf(py1, gy1), 0.0f);
        float inter = iw * ih;
        iou[b] = inter / (pa + ga - inter + 1e-6f);

        float dx = b0 - tv[0], dy = b1 - tv[1];
        dxy[b] = dx * dx + dy * dy;
        float sw = sqrtf(fmaxf(b2, 0.0f)) - sqrtf(fmaxf(tv[2], 0.0f));
        float sh = sqrtf(fmaxf(b3, 0.0f)) - sqrtf(fmaxf(tv[3], 0.0f));
        dwh[b] = sw * sw + sh * sh;
        conf[b] = b4;
    }

    int best = (iou[1] > iou[0]) ? 1 : 0;   // argmax ties -> first (box 0)

    float loss = 0.0f;
    #pragma unroll
    for (int b = 0; b < 2; ++b) {
        float resp_obj = (b == best) ? obj : 0.0f;
        loss += 5.0f * resp_obj * (dxy[b] + dwh[b]);          // coord
        float d = conf[b] - iou[b];
        loss += resp_obj * d * d;                              // conf obj
        loss += 0.5f * (1.0f - resp_obj) * conf[b] * conf[b];  // conf noobj
    }

    float cls = 0.0f;
    #pragma unroll
    for (int c = 0; c < 20; ++c) {
        float d = pv[10 + c] - tv[5 + c];
        cls += d * d;
    }
    loss += obj * cls;                                          // class

    // ---- wave64 + block reduce ----
    #pragma unroll
    for (int off = 32; off > 0; off >>= 1)
        loss += __shfl_down(loss, off, 64);

    __shared__ float smem[4];
    int lane = t & 63;
    int wid  = t >> 6;
    if (lane == 0) smem[wid] = loss;
    __syncthreads();
    if (t == 0)
        partial[blockIdx.x] = smem[0] + smem[1] + smem[2] + smem[3];
}

__global__ __launch_bounds__(256) void yolo_final_kernel(
    const float* __restrict__ partial, int n, float* __restrict__ out, float invN)
{
    float s = 0.0f;
    for (int i = threadIdx.x; i < n; i += 256)
        s += partial[i];
    #pragma unroll
    for (int off = 32; off > 0; off >>= 1)
        s += __shfl_down(s, off, 64);

    __shared__ float smem[4];
    int lane = threadIdx.x & 63;
    int wid  = threadIdx.x >> 6;
    if (lane == 0) smem[wid] = s;
    __syncthreads();
    if (threadIdx.x == 0)
        out[0] = (smem[0] + smem[1] + smem[2] + smem[3]) * invN;
}

extern "C" void kernel_launch(void* const* d_in, const int* in_sizes, int n_in,
                              void* d_out, int out_size, void* d_ws, size_t ws_size,
                              hipStream_t stream)
{
    const float* pred = (const float*)d_in[0];
    const float* tgt  = (const float*)d_in[1];
    float* out        = (float*)d_out;
    float* partial    = (float*)d_ws;

    int ncells = in_sizes[0] / CELL_P;     // N*S*S = 802816 = 256 * 3136 exactly
    int N      = ncells / 49;
    int blocks = ncells / 256;             // 3136, no tail

    yolo_cell_kernel<<<blocks, 256, 0, stream>>>(pred, tgt, partial);
    yolo_final_kernel<<<1, 256, 0, stream>>>(partial, blocks, out, 1.0f / (float)N);
}